// Round 6
// baseline (139.060 us; speedup 1.0000x reference)
//
#include <hip/hip_runtime.h>
#include <hip/hip_bf16.h>
#include <stdint.h>

#define T_TOK 2048
#define DHID  1024
#define NEXP  16
#define MR    256
#define MS    512
#define CAP   512

typedef float  f32x4  __attribute__((ext_vector_type(4)));
typedef __bf16 bf16x8 __attribute__((ext_vector_type(8)));

typedef __attribute__((address_space(3))) void       lds_void;
typedef const __attribute__((address_space(1))) void gbl_void;

#define GLOAD16(g, l) __builtin_amdgcn_global_load_lds((gbl_void*)(g), (lds_void*)(l), 16, 0, 0)

__device__ __forceinline__ ushort f2bf(float f) {
  uint32_t u = __float_as_uint(f);
  u = (u + 0x7fffu + ((u >> 16) & 1u)) >> 16;
  return (ushort)u;
}
__device__ __forceinline__ float bf2f(ushort v) { return __uint_as_float(((uint32_t)v) << 16); }

// bijective XCD swizzle (requires nwg % 8 == 0): contiguous logical ids -> same XCD
__device__ __forceinline__ int xcd_swz(int b, int cpx) { return (b & 7) * cpx + (b >> 3); }

// ---- stage 128x64 bf16 tile (16 KB) from row-major global into linear LDS ----
__device__ __forceinline__ void stage_lin(const ushort* __restrict__ g0, int strideE,
                                          ushort* lds, int tid) {
  const int wave = tid >> 6;
  const int r = tid >> 3, colE = (tid & 7) * 8;
#pragma unroll
  for (int s = 0; s < 4; ++s)
    GLOAD16(g0 + (size_t)(s * 32 + r) * strideE + colE, lds + s * 2048 + wave * 512);
}

__device__ __forceinline__ void stage_gather(const ushort* __restrict__ xb,
                                             const int tok[4], int k0,
                                             ushort* lds, int tid) {
  const int wave = tid >> 6;
  const int colE = (tid & 7) * 8;
#pragma unroll
  for (int s = 0; s < 4; ++s)
    GLOAD16(xb + (size_t)tok[s] * DHID + k0 + colE, lds + s * 2048 + wave * 512);
}

// ---- one BK=64 step: wave (wr,wc) computes 64x64 via 4x4 16x16 frags ----
__device__ __forceinline__ void mfma_tile(const ushort* a_sh, const ushort* b_sh,
                                          int wr, int wc, int lane, f32x4 (&acc)[4][4]) {
  const int rb = lane & 15;
#pragma unroll
  for (int kk = 0; kk < 64; kk += 32) {
    const int k8 = kk + ((lane >> 4) << 3);
    bf16x8 af[4];
#pragma unroll
    for (int m = 0; m < 4; m++)
      af[m] = *(const bf16x8*)&a_sh[(wr * 64 + m * 16 + rb) * 64 + k8];
#pragma unroll
    for (int n = 0; n < 4; n++) {
      bf16x8 bf = *(const bf16x8*)&b_sh[(wc * 64 + n * 16 + rb) * 64 + k8];
#pragma unroll
      for (int m = 0; m < 4; m++)
        acc[m][n] = __builtin_amdgcn_mfma_f32_16x16x32_bf16(af[m], bf, acc[m][n], 0, 0, 0);
    }
  }
}

// ---------------- x->bf16 + fp32 router; 16 tokens per block ----------------
__global__ __launch_bounds__(256) void k_prep(
    const float* __restrict__ x, const float* __restrict__ rw,
    ushort* __restrict__ xb, int* __restrict__ topi, float2* __restrict__ topw)
{
  __shared__ float rw_sh[NEXP][DHID];
  const int tid = threadIdx.x;
#pragma unroll
  for (int it = 0; it < 16; ++it) {
    const int flat = it * 1024 + tid * 4;
    float4 v = *(const float4*)&rw[flat];
    const int d = flat >> 4, e = flat & 15;
    rw_sh[e + 0][d] = v.x; rw_sh[e + 1][d] = v.y;
    rw_sh[e + 2][d] = v.z; rw_sh[e + 3][d] = v.w;
  }
  __syncthreads();

  const int wave = tid >> 6, lane = tid & 63;
  for (int tk = 0; tk < 4; ++tk) {
    const int t = blockIdx.x * 16 + wave * 4 + tk;
    const float* xp = x + (size_t)t * DHID;
    float acc[NEXP];
#pragma unroll
    for (int e = 0; e < NEXP; e++) acc[e] = 0.f;
#pragma unroll
    for (int i = 0; i < 4; ++i) {
      const int d4 = i * 64 + lane;
      float4 xv = *(const float4*)&xp[d4 * 4];
      ushort4 o; o.x = f2bf(xv.x); o.y = f2bf(xv.y); o.z = f2bf(xv.z); o.w = f2bf(xv.w);
      *(ushort4*)&xb[(size_t)t * DHID + d4 * 4] = o;
#pragma unroll
      for (int e = 0; e < NEXP; e++) {
        float4 wv = *(const float4*)&rw_sh[e][d4 * 4];
        acc[e] = fmaf(xv.x, wv.x, acc[e]);
        acc[e] = fmaf(xv.y, wv.y, acc[e]);
        acc[e] = fmaf(xv.z, wv.z, acc[e]);
        acc[e] = fmaf(xv.w, wv.w, acc[e]);
      }
    }
#pragma unroll
    for (int off = 32; off >= 1; off >>= 1) {
#pragma unroll
      for (int e = 0; e < NEXP; e++) acc[e] += __shfl_xor(acc[e], off, 64);
    }
    if (lane == 0) {
      float m = acc[0];
#pragma unroll
      for (int e = 1; e < NEXP; e++) m = fmaxf(m, acc[e]);
      float p[NEXP], Z = 0.f;
#pragma unroll
      for (int e = 0; e < NEXP; e++) { p[e] = __expf(acc[e] - m); Z += p[e]; }
      const float inv = 1.f / Z;
      int i1 = 0; float p1 = p[0] * inv;
      for (int e = 1; e < NEXP; e++) { float pe = p[e] * inv; if (pe > p1) { p1 = pe; i1 = e; } }
      int i2 = -1; float p2 = -1.f;
      for (int e = 0; e < NEXP; e++) { if (e == i1) continue; float pe = p[e] * inv; if (pe > p2) { p2 = pe; i2 = e; } }
      const float denom = p1 + p2 + 1e-9f;
      topi[t] = i1 | (i2 << 8);
      topw[t] = make_float2(p1 / denom, p2 / denom);
    }
  }
}

// ---------------- per-expert compacted lists + token->slot map (no atomics) ----------------
__global__ __launch_bounds__(256) void k_build(
    const int* __restrict__ topi, const float2* __restrict__ topw,
    int* __restrict__ cnt, int* __restrict__ ltok, float* __restrict__ lw,
    int* __restrict__ tslot)
{
  __shared__ int wsum[4];
  const int e = blockIdx.x;
  const int tid = threadIdx.x, wave = tid >> 6, lane = tid & 63;
  const int t0 = tid * 8;

  int4 a = *(const int4*)&topi[t0];
  int4 b = *(const int4*)&topi[t0 + 4];
  int ti[8] = {a.x, a.y, a.z, a.w, b.x, b.y, b.z, b.w};
  int match[8]; int c = 0;
#pragma unroll
  for (int k = 0; k < 8; ++k) {
    const int i1 = ti[k] & 0xff, i2 = (ti[k] >> 8) & 0xff;
    match[k] = (i1 == e) ? 1 : ((i2 == e) ? 2 : 0);
    c += (match[k] != 0);
  }
  int incl = c;
#pragma unroll
  for (int off = 1; off < 64; off <<= 1) {
    int n = __shfl_up(incl, off, 64);
    if (lane >= off) incl += n;
  }
  if (lane == 63) wsum[wave] = incl;
  __syncthreads();
  int base = incl - c;
  for (int w = 0; w < wave; ++w) base += wsum[w];
  if (tid == 0) {
    int tot = wsum[0] + wsum[1] + wsum[2] + wsum[3];
    cnt[e] = tot > CAP ? CAP : tot;
  }
#pragma unroll
  for (int k = 0; k < 8; ++k) {
    if (match[k]) {
      const int t = t0 + k;
      if (base < CAP) {
        float2 w2 = topw[t];
        ltok[e * CAP + base] = t;
        lw[e * CAP + base] = (match[k] == 1) ? w2.x : w2.y;
        tslot[t * 2 + (match[k] - 1)] = e * CAP + base;
      } else {
        tslot[t * 2 + (match[k] - 1)] = -1;
      }
      base++;
    }
  }
}

// ---------------- merged transpose+convert (6 mats), optional 16-row g/u interleave ----------------
struct TP {
  const float* in; ushort* out;
  int R, C, out_ld, ilv;
  long long out_batch;
  int end;
};

__global__ __launch_bounds__(256) void k_tpose(TP p0, TP p1, TP p2, TP p3, TP p4, TP p5) {
  const int bid = blockIdx.x;
  TP p; int base;
  if      (bid < p0.end) { p = p0; base = 0; }
  else if (bid < p1.end) { p = p1; base = p0.end; }
  else if (bid < p2.end) { p = p2; base = p1.end; }
  else if (bid < p3.end) { p = p3; base = p2.end; }
  else if (bid < p4.end) { p = p4; base = p3.end; }
  else                   { p = p5; base = p4.end; }
  const int local = bid - base;
  const int tr = p.R >> 6, tc = p.C >> 6, per = tr * tc;
  const int b = local / per, rem = local - b * per;
  const int rt = rem / tc, ct = rem - rt * tc;
  const int r0 = rt * 64, c0 = ct * 64;
  const float* ip = p.in + (size_t)b * p.R * p.C;
  ushort* op = p.out + (size_t)b * p.out_batch;

  __shared__ float t_sh[64][65];
  const int tid = threadIdx.x;
  const int trd = tid >> 4, tcd = (tid & 15) * 4;
#pragma unroll
  for (int q = 0; q < 4; q++) {
    float4 v = *(const float4*)&ip[(size_t)(r0 + trd + q * 16) * p.C + c0 + tcd];
    t_sh[trd + q * 16][tcd + 0] = v.x; t_sh[trd + q * 16][tcd + 1] = v.y;
    t_sh[trd + q * 16][tcd + 2] = v.z; t_sh[trd + q * 16][tcd + 3] = v.w;
  }
  __syncthreads();
#pragma unroll
  for (int q = 0; q < 4; q++) {
    const int cc = trd + q * 16;
    int rr = c0 + cc;
    if (p.ilv) rr = ((rr >> 4) << 5) + (rr & 15);   // 16-row g/u interleave slot
    ushort4 o;
    o.x = f2bf(t_sh[tcd + 0][cc]); o.y = f2bf(t_sh[tcd + 1][cc]);
    o.z = f2bf(t_sh[tcd + 2][cc]); o.w = f2bf(t_sh[tcd + 3][cc]);
    *(ushort4*)&op[(size_t)rr * p.out_ld + r0 + tcd] = o;
  }
}

// ---------------- up GEMMs + fused silu*u epilogue (double-buffered staging) ----------------
__global__ __launch_bounds__(256) void k_up(
    const ushort* __restrict__ xb, const ushort* __restrict__ wguTs,
    const ushort* __restrict__ wguTr, const int* __restrict__ cnt,
    const int* __restrict__ ltok, const float* __restrict__ lw,
    ushort* __restrict__ h_s, ushort* __restrict__ h_r)
{
  __shared__ ushort a_sh[2][128 * 64], b_sh[2][128 * 64];   // 64 KB exactly
  ushort (*r_sh)[64] = (ushort(*)[64])&a_sh[0][0];          // epilogue alias
  const int tid = threadIdx.x, lane = tid & 63, wave = tid >> 6;
  const int wr = wave >> 1, wc = wave & 1;
  const int rb = lane & 15, rowoff = (lane >> 4) << 2;
  f32x4 acc[4][4] = {};
  const int bid = xcd_swz(blockIdx.x, 64);   // 512 blocks

  if (bid < 256) {
    const int mt = bid & 15, nt = bid >> 4;
    const ushort* Ab = xb + (size_t)mt * 128 * DHID;
    const ushort* Bb = wguTs + (size_t)nt * 128 * DHID;
    stage_lin(Ab, DHID, a_sh[0], tid);
    stage_lin(Bb, DHID, b_sh[0], tid);
    __syncthreads();
    int cur = 0;
    for (int t = 0; t < 16; ++t) {
      if (t < 15) {
        stage_lin(Ab + (t + 1) * 64, DHID, a_sh[cur ^ 1], tid);
        stage_lin(Bb + (t + 1) * 64, DHID, b_sh[cur ^ 1], tid);
      }
      mfma_tile(a_sh[cur], b_sh[cur], wr, wc, lane, acc);
      __syncthreads();          // drains vmcnt(0)+lgkmcnt(0): next buf ready, cur free
      cur ^= 1;
    }
#pragma unroll
    for (int m = 0; m < 4; m++)
#pragma unroll
      for (int p = 0; p < 2; p++) {
        f32x4 g = acc[m][2 * p], u = acc[m][2 * p + 1];
#pragma unroll
        for (int jj = 0; jj < 4; jj++) {
          float gv = g[jj];
          float hv = (gv / (1.f + __expf(-gv))) * u[jj];
          r_sh[wr * 64 + m * 16 + rowoff + jj][wc * 32 + p * 16 + rb] = f2bf(hv);
        }
      }
    __syncthreads();
#pragma unroll
    for (int sp = 0; sp < 4; sp++) {
      const int row = sp * 32 + (tid >> 3), col = (tid & 7) * 8;
      *(uint4*)&h_s[(size_t)(mt * 128 + row) * DHID + nt * 64 + col] = *(const uint4*)&r_sh[row][col];
    }
  } else {
    const int id = bid - 256;
    const int e = id >> 4, st = (id >> 2) & 3, ntile = id & 3;
    const int c = cnt[e], s0 = st * 128;
    if (s0 >= c) return;
    int tok[4];
#pragma unroll
    for (int s = 0; s < 4; ++s) {
      int slot = s0 + s * 32 + (tid >> 3);
      if (slot >= c) slot = c - 1;
      tok[s] = ltok[e * CAP + slot];
    }
    const ushort* Bb = wguTr + ((size_t)e * 512 + ntile * 128) * DHID;
    stage_gather(xb, tok, 0, a_sh[0], tid);
    stage_lin(Bb, DHID, b_sh[0], tid);
    __syncthreads();
    int cur = 0;
    for (int t = 0; t < 16; ++t) {
      if (t < 15) {
        stage_gather(xb, tok, (t + 1) * 64, a_sh[cur ^ 1], tid);
        stage_lin(Bb + (t + 1) * 64, DHID, b_sh[cur ^ 1], tid);
      }
      mfma_tile(a_sh[cur], b_sh[cur], wr, wc, lane, acc);
      __syncthreads();
      cur ^= 1;
    }
#pragma unroll
    for (int m = 0; m < 4; m++) {
#pragma unroll
      for (int jj = 0; jj < 4; jj++) {
        const int slot = s0 + wr * 64 + m * 16 + rowoff + jj;
        const float w = (slot < c) ? lw[e * CAP + slot] : 0.f;
#pragma unroll
        for (int p = 0; p < 2; p++) {
          float gv = acc[m][2 * p][jj];
          float hv = (gv / (1.f + __expf(-gv))) * acc[m][2 * p + 1][jj] * w;
          r_sh[wr * 64 + m * 16 + rowoff + jj][wc * 32 + p * 16 + rb] = f2bf(hv);
        }
      }
    }
    __syncthreads();
#pragma unroll
    for (int sp = 0; sp < 4; sp++) {
      const int row = sp * 32 + (tid >> 3), col = (tid & 7) * 8;
      *(uint4*)&h_r[((size_t)e * CAP + s0 + row) * MR + ntile * 64 + col] = *(const uint4*)&r_sh[row][col];
    }
  }
}

// ---------------- down GEMMs (merged, double-buffered): bf16 partials, no atomics ----------------
__global__ __launch_bounds__(256) void k_down(
    const ushort* __restrict__ h_s, const ushort* __restrict__ wdTs,
    const ushort* __restrict__ h_r, const ushort* __restrict__ wdTr,
    const int* __restrict__ cnt, ushort* __restrict__ ds, ushort* __restrict__ dr)
{
  __shared__ ushort a_sh[2][128 * 64], b_sh[2][128 * 64];   // 64 KB exactly
  ushort (*r_sh)[64] = (ushort(*)[64])&a_sh[0][0];
  const int tid = threadIdx.x, lane = tid & 63, wave = tid >> 6;
  const int wr = wave >> 1, wc = wave & 1;
  const int rb = lane & 15, rowoff = (lane >> 4) << 2;
  f32x4 acc[4][4] = {};
  const int bid = xcd_swz(blockIdx.x, 80);   // 640 blocks

  const ushort* Ab; const ushort* Bb;
  int K, rowbase, colbase; ushort* outp;
  if (bid < 128) {
    const int mt = bid >> 3, nt = bid & 7;
    Ab = h_s + (size_t)mt * 128 * DHID;
    Bb = wdTs + (size_t)nt * 128 * DHID;
    K = DHID; rowbase = mt * 128; colbase = nt * 128;
    outp = ds;
  } else {
    const int id = bid - 128;
    const int e = id >> 5, st = (id >> 3) & 3, nt = id & 7;
    const int c = cnt[e], s0 = st * 128;
    if (s0 >= c) return;
    Ab = h_r + ((size_t)e * CAP + s0) * MR;
    Bb = wdTr + ((size_t)e * DHID + nt * 128) * MR;
    K = MR; rowbase = e * CAP + s0; colbase = nt * 128;
    outp = dr;
  }
  const int nk = K >> 6;
  stage_lin(Ab, K, a_sh[0], tid);
  stage_lin(Bb, K, b_sh[0], tid);
  __syncthreads();
  int cur = 0;
  for (int t = 0; t < nk; ++t) {
    if (t + 1 < nk) {
      stage_lin(Ab + (t + 1) * 64, K, a_sh[cur ^ 1], tid);
      stage_lin(Bb + (t + 1) * 64, K, b_sh[cur ^ 1], tid);
    }
    mfma_tile(a_sh[cur], b_sh[cur], wr, wc, lane, acc);
    __syncthreads();
    cur ^= 1;
  }
#pragma unroll
  for (int p = 0; p < 2; p++) {
    __syncthreads();
#pragma unroll
    for (int m = 0; m < 4; m++)
#pragma unroll
      for (int h = 0; h < 2; h++) {
        f32x4 v = acc[m][2 * p + h];
#pragma unroll
        for (int jj = 0; jj < 4; jj++)
          r_sh[wr * 64 + m * 16 + rowoff + jj][wc * 32 + h * 16 + rb] = f2bf(v[jj]);
      }
    __syncthreads();
#pragma unroll
    for (int sp = 0; sp < 4; sp++) {
      const int row = sp * 32 + (tid >> 3), cc = (tid & 7) * 8;
      const int gcol = colbase + (cc >> 5) * 64 + p * 32 + (cc & 31);
      *(uint4*)&outp[(size_t)(rowbase + row) * DHID + gcol] = *(const uint4*)&r_sh[row][cc];
    }
  }
}

// ---------------- combine: out[t] = ds[t] + dr[es1] + dr[es2]  (f32 out) ----------------
__global__ __launch_bounds__(256) void k_comb(
    const ushort* __restrict__ ds, const ushort* __restrict__ dr,
    const int* __restrict__ tslot, float* __restrict__ out)
{
  const int tid = threadIdx.x;
  const int t = blockIdx.x * 2 + (tid >> 7);
  const int d = (tid & 127) * 8;
  const int es1 = tslot[t * 2], es2 = tslot[t * 2 + 1];
  uint4 a = *(const uint4*)&ds[(size_t)t * DHID + d];
  float r[8];
  const ushort* ap = (const ushort*)&a;
#pragma unroll
  for (int k = 0; k < 8; ++k) r[k] = bf2f(ap[k]);
  if (es1 >= 0) {
    uint4 b = *(const uint4*)&dr[(size_t)es1 * DHID + d];
    const ushort* bp = (const ushort*)&b;
#pragma unroll
    for (int k = 0; k < 8; ++k) r[k] += bf2f(bp[k]);
  }
  if (es2 >= 0) {
    uint4 b = *(const uint4*)&dr[(size_t)es2 * DHID + d];
    const ushort* bp = (const ushort*)&b;
#pragma unroll
    for (int k = 0; k < 8; ++k) r[k] += bf2f(bp[k]);
  }
  float4* op = (float4*)&out[(size_t)t * DHID + d];
  op[0] = make_float4(r[0], r[1], r[2], r[3]);
  op[1] = make_float4(r[4], r[5], r[6], r[7]);
}

extern "C" void kernel_launch(void* const* d_in, const int* in_sizes, int n_in,
                              void* d_out, int out_size, void* d_ws, size_t ws_size,
                              hipStream_t stream) {
  const float* x    = (const float*)d_in[0];
  const float* rw   = (const float*)d_in[1];
  const float* wg_r = (const float*)d_in[2];
  const float* wu_r = (const float*)d_in[3];
  const float* wd_r = (const float*)d_in[4];
  const float* wg_s = (const float*)d_in[5];
  const float* wu_s = (const float*)d_in[6];
  const float* wd_s = (const float*)d_in[7];
  float* out = (float*)d_out;

  char* ws = (char*)d_ws;
  size_t off = 0;
  ushort* xb    = (ushort*)(ws + off); off += (size_t)T_TOK * DHID * 2;        // 4 MB
  ushort* wguTs = (ushort*)(ws + off); off += (size_t)2048 * DHID * 2;         // 4 MB  interleaved g/u rows
  ushort* wdTs  = (ushort*)(ws + off); off += (size_t)DHID * DHID * 2;         // 2 MB
  ushort* wguTr = (ushort*)(ws + off); off += (size_t)NEXP * 512 * DHID * 2;   // 16 MB interleaved per expert
  ushort* wdTr  = (ushort*)(ws + off); off += (size_t)NEXP * DHID * MR * 2;    // 8 MB
  ushort* h_s   = (ushort*)(ws + off); off += (size_t)T_TOK * DHID * 2;        // 4 MB
  ushort* h_r   = (ushort*)(ws + off); off += (size_t)NEXP * CAP * MR * 2;     // 4 MB
  ushort* ds    = (ushort*)(ws + off); off += (size_t)T_TOK * DHID * 2;        // 4 MB
  ushort* dr    = (ushort*)(ws + off); off += (size_t)NEXP * CAP * DHID * 2;   // 16 MB
  int*    cnt   = (int*)(ws + off);    off += 256;
  int*    ltok  = (int*)(ws + off);    off += (size_t)NEXP * CAP * 4;
  float*  lw    = (float*)(ws + off);  off += (size_t)NEXP * CAP * 4;
  int*    topi  = (int*)(ws + off);    off += (size_t)T_TOK * 4;
  float2* topw  = (float2*)(ws + off); off += (size_t)T_TOK * 8;
  int*    tslot = (int*)(ws + off);    off += (size_t)T_TOK * 2 * 4;
  if (off > ws_size) return;

  k_prep<<<T_TOK / 16, 256, 0, stream>>>(x, rw, xb, topi, topw);
  k_build<<<NEXP, 256, 0, stream>>>(topi, topw, cnt, ltok, lw, tslot);

  TP p0 = {wg_r, wguTr,             DHID, MR,   DHID, 1, (long long)512 * DHID,  1024};
  TP p1 = {wu_r, wguTr + 16 * DHID, DHID, MR,   DHID, 1, (long long)512 * DHID,  2048};
  TP p2 = {wd_r, wdTr,              MR,   DHID, MR,   0, (long long)DHID * MR,   3072};
  TP p3 = {wg_s, wguTs,             DHID, MS,   DHID, 1, (long long)1024 * DHID, 3328};
  TP p4 = {wu_s, wguTs + 16 * DHID, DHID, MS,   DHID, 1, (long long)1024 * DHID, 3584};
  TP p5 = {wd_s, wdTs,              MS,   DHID, DHID, 0, (long long)MS,          3840};
  k_tpose<<<3840, 256, 0, stream>>>(p0, p1, p2, p3, p4, p5);

  k_up<<<512, 256, 0, stream>>>(xb, wguTs, wguTr, cnt, ltok, lw, h_s, h_r);
  k_down<<<640, 256, 0, stream>>>(h_s, wdTs, h_r, wdTr, cnt, ds, dr);
  k_comb<<<T_TOK / 2, 256, 0, stream>>>(ds, dr, tslot, out);
}

// Round 7
// 118.080 us; speedup vs baseline: 1.1777x; 1.1777x over previous
//
#include <hip/hip_runtime.h>
#include <hip/hip_bf16.h>
#include <stdint.h>

#define T_TOK 2048
#define DHID  1024
#define NEXP  16
#define MR    256
#define MS    512
#define CAP   512
#define QMAX  80   // max routed M-tiles: sum ceil(cnt/64) <= 4096/64 + 16

typedef float  f32x4  __attribute__((ext_vector_type(4)));
typedef __bf16 bf16x8 __attribute__((ext_vector_type(8)));

typedef __attribute__((address_space(3))) void       lds_void;
typedef const __attribute__((address_space(1))) void gbl_void;

#define GLOAD16(g, l) __builtin_amdgcn_global_load_lds((gbl_void*)(g), (lds_void*)(l), 16, 0, 0)

__device__ __forceinline__ ushort f2bf(float f) {
  uint32_t u = __float_as_uint(f);
  u = (u + 0x7fffu + ((u >> 16) & 1u)) >> 16;
  return (ushort)u;
}
__device__ __forceinline__ float bf2f(ushort v) { return __uint_as_float(((uint32_t)v) << 16); }

// bijective XCD swizzle (nwg % 8 == 0): hw round-robin -> contiguous logical chunk per XCD
__device__ __forceinline__ int xcd_swz(int b, int cpx) { return (b & 7) * cpx + (b >> 3); }

// ---- stage 128x64 bf16 tile (16 KB) into linear LDS: 4 shots of 32 rows ----
__device__ __forceinline__ void stage128(const ushort* __restrict__ g0, int strideE,
                                         ushort* lds, int tid) {
  const int wave = tid >> 6;
  const int r = tid >> 3, colE = (tid & 7) * 8;
#pragma unroll
  for (int s = 0; s < 4; ++s)
    GLOAD16(g0 + (size_t)(s * 32 + r) * strideE + colE, lds + s * 2048 + wave * 512);
}

// ---- stage 64x64 bf16 tile (8 KB): 2 shots of 32 rows ----
__device__ __forceinline__ void stage64(const ushort* __restrict__ g0, int strideE,
                                        ushort* lds, int tid) {
  const int wave = tid >> 6;
  const int r = tid >> 3, colE = (tid & 7) * 8;
#pragma unroll
  for (int s = 0; s < 2; ++s)
    GLOAD16(g0 + (size_t)(s * 32 + r) * strideE + colE, lds + s * 2048 + wave * 512);
}

// gathered 64 rows from xb by token list
__device__ __forceinline__ void stage_gather64(const ushort* __restrict__ xb,
                                               const int tok[2], int k0,
                                               ushort* lds, int tid) {
  const int wave = tid >> 6;
  const int colE = (tid & 7) * 8;
#pragma unroll
  for (int s = 0; s < 2; ++s)
    GLOAD16(xb + (size_t)tok[s] * DHID + k0 + colE, lds + s * 2048 + wave * 512);
}

// ---- one BK=64 step of a 64x128 tile: wave (wr,wc) computes 32x64 via 2x4 frags ----
__device__ __forceinline__ void mfma_tile64(const ushort* a_sh, const ushort* b_sh,
                                            int wr, int wc, int lane, f32x4 (&acc)[2][4]) {
  const int rb = lane & 15;
#pragma unroll
  for (int kk = 0; kk < 64; kk += 32) {
    const int k8 = kk + ((lane >> 4) << 3);
    bf16x8 af[2];
#pragma unroll
    for (int m = 0; m < 2; m++)
      af[m] = *(const bf16x8*)&a_sh[(wr * 32 + m * 16 + rb) * 64 + k8];
#pragma unroll
    for (int n = 0; n < 4; n++) {
      bf16x8 bf = *(const bf16x8*)&b_sh[(wc * 64 + n * 16 + rb) * 64 + k8];
#pragma unroll
      for (int m = 0; m < 2; m++)
        acc[m][n] = __builtin_amdgcn_mfma_f32_16x16x32_bf16(af[m], bf, acc[m][n], 0, 0, 0);
    }
  }
}

// ---------------- x->bf16 + fp32 router; 16 tokens per block ----------------
__global__ __launch_bounds__(256) void k_prep(
    const float* __restrict__ x, const float* __restrict__ rw,
    ushort* __restrict__ xb, int* __restrict__ topi, float2* __restrict__ topw)
{
  __shared__ float rw_sh[NEXP][DHID];
  const int tid = threadIdx.x;
#pragma unroll
  for (int it = 0; it < 16; ++it) {
    const int flat = it * 1024 + tid * 4;
    float4 v = *(const float4*)&rw[flat];
    const int d = flat >> 4, e = flat & 15;
    rw_sh[e + 0][d] = v.x; rw_sh[e + 1][d] = v.y;
    rw_sh[e + 2][d] = v.z; rw_sh[e + 3][d] = v.w;
  }
  __syncthreads();

  const int wave = tid >> 6, lane = tid & 63;
  for (int tk = 0; tk < 4; ++tk) {
    const int t = blockIdx.x * 16 + wave * 4 + tk;
    const float* xp = x + (size_t)t * DHID;
    float acc[NEXP];
#pragma unroll
    for (int e = 0; e < NEXP; e++) acc[e] = 0.f;
#pragma unroll
    for (int i = 0; i < 4; ++i) {
      const int d4 = i * 64 + lane;
      float4 xv = *(const float4*)&xp[d4 * 4];
      ushort4 o; o.x = f2bf(xv.x); o.y = f2bf(xv.y); o.z = f2bf(xv.z); o.w = f2bf(xv.w);
      *(ushort4*)&xb[(size_t)t * DHID + d4 * 4] = o;
#pragma unroll
      for (int e = 0; e < NEXP; e++) {
        float4 wv = *(const float4*)&rw_sh[e][d4 * 4];
        acc[e] = fmaf(xv.x, wv.x, acc[e]);
        acc[e] = fmaf(xv.y, wv.y, acc[e]);
        acc[e] = fmaf(xv.z, wv.z, acc[e]);
        acc[e] = fmaf(xv.w, wv.w, acc[e]);
      }
    }
#pragma unroll
    for (int off = 32; off >= 1; off >>= 1) {
#pragma unroll
      for (int e = 0; e < NEXP; e++) acc[e] += __shfl_xor(acc[e], off, 64);
    }
    if (lane == 0) {
      float m = acc[0];
#pragma unroll
      for (int e = 1; e < NEXP; e++) m = fmaxf(m, acc[e]);
      float p[NEXP], Z = 0.f;
#pragma unroll
      for (int e = 0; e < NEXP; e++) { p[e] = __expf(acc[e] - m); Z += p[e]; }
      const float inv = 1.f / Z;
      int i1 = 0; float p1 = p[0] * inv;
      for (int e = 1; e < NEXP; e++) { float pe = p[e] * inv; if (pe > p1) { p1 = pe; i1 = e; } }
      int i2 = -1; float p2 = -1.f;
      for (int e = 0; e < NEXP; e++) { if (e == i1) continue; float pe = p[e] * inv; if (pe > p2) { p2 = pe; i2 = e; } }
      const float denom = p1 + p2 + 1e-9f;
      topi[t] = i1 | (i2 << 8);
      topw[t] = make_float2(p1 / denom, p2 / denom);
    }
  }
}

// ---------------- per-expert compacted lists + token->slot map (no atomics) ----------------
__global__ __launch_bounds__(256) void k_build(
    const int* __restrict__ topi, const float2* __restrict__ topw,
    int* __restrict__ cnt, int* __restrict__ ltok, float* __restrict__ lw,
    int* __restrict__ tslot)
{
  __shared__ int wsum[4];
  const int e = blockIdx.x;
  const int tid = threadIdx.x, wave = tid >> 6, lane = tid & 63;
  const int t0 = tid * 8;

  int4 a = *(const int4*)&topi[t0];
  int4 b = *(const int4*)&topi[t0 + 4];
  int ti[8] = {a.x, a.y, a.z, a.w, b.x, b.y, b.z, b.w};
  int match[8]; int c = 0;
#pragma unroll
  for (int k = 0; k < 8; ++k) {
    const int i1 = ti[k] & 0xff, i2 = (ti[k] >> 8) & 0xff;
    match[k] = (i1 == e) ? 1 : ((i2 == e) ? 2 : 0);
    c += (match[k] != 0);
  }
  int incl = c;
#pragma unroll
  for (int off = 1; off < 64; off <<= 1) {
    int n = __shfl_up(incl, off, 64);
    if (lane >= off) incl += n;
  }
  if (lane == 63) wsum[wave] = incl;
  __syncthreads();
  int base = incl - c;
  for (int w = 0; w < wave; ++w) base += wsum[w];
  if (tid == 0) {
    int tot = wsum[0] + wsum[1] + wsum[2] + wsum[3];
    cnt[e] = tot > CAP ? CAP : tot;
  }
#pragma unroll
  for (int k = 0; k < 8; ++k) {
    if (match[k]) {
      const int t = t0 + k;
      if (base < CAP) {
        float2 w2 = topw[t];
        ltok[e * CAP + base] = t;
        lw[e * CAP + base] = (match[k] == 1) ? w2.x : w2.y;
        tslot[t * 2 + (match[k] - 1)] = e * CAP + base;
      } else {
        tslot[t * 2 + (match[k] - 1)] = -1;
      }
      base++;
    }
  }
}

// ---------------- compact routed M-tile queue: desc[i] = (e<<16)|s0 ----------------
__global__ void k_queue(const int* __restrict__ cnt, int* __restrict__ desc, int* __restrict__ nmt) {
  if (threadIdx.x == 0) {
    int n = 0;
    for (int e = 0; e < NEXP; ++e)
      for (int s0 = 0; s0 < cnt[e]; s0 += 64)
        if (n < QMAX) desc[n++] = (e << 16) | s0;
    *nmt = n;
  }
}

// ---------------- merged transpose+convert (6 mats), optional 16-row g/u interleave ----------------
struct TP {
  const float* in; ushort* out;
  int R, C, out_ld, ilv;
  long long out_batch;
  int end;
};

__global__ __launch_bounds__(256) void k_tpose(TP p0, TP p1, TP p2, TP p3, TP p4, TP p5) {
  const int bid = blockIdx.x;
  TP p; int base;
  if      (bid < p0.end) { p = p0; base = 0; }
  else if (bid < p1.end) { p = p1; base = p0.end; }
  else if (bid < p2.end) { p = p2; base = p1.end; }
  else if (bid < p3.end) { p = p3; base = p2.end; }
  else if (bid < p4.end) { p = p4; base = p3.end; }
  else                   { p = p5; base = p4.end; }
  const int local = bid - base;
  const int tr = p.R >> 6, tc = p.C >> 6, per = tr * tc;
  const int b = local / per, rem = local - b * per;
  const int rt = rem / tc, ct = rem - rt * tc;
  const int r0 = rt * 64, c0 = ct * 64;
  const float* ip = p.in + (size_t)b * p.R * p.C;
  ushort* op = p.out + (size_t)b * p.out_batch;

  __shared__ float t_sh[64][65];
  const int tid = threadIdx.x;
  const int trd = tid >> 4, tcd = (tid & 15) * 4;
#pragma unroll
  for (int q = 0; q < 4; q++) {
    float4 v = *(const float4*)&ip[(size_t)(r0 + trd + q * 16) * p.C + c0 + tcd];
    t_sh[trd + q * 16][tcd + 0] = v.x; t_sh[trd + q * 16][tcd + 1] = v.y;
    t_sh[trd + q * 16][tcd + 2] = v.z; t_sh[trd + q * 16][tcd + 3] = v.w;
  }
  __syncthreads();
#pragma unroll
  for (int q = 0; q < 4; q++) {
    const int cc = trd + q * 16;
    int rr = c0 + cc;
    if (p.ilv) rr = ((rr >> 4) << 5) + (rr & 15);   // 16-row g/u interleave slot
    ushort4 o;
    o.x = f2bf(t_sh[tcd + 0][cc]); o.y = f2bf(t_sh[tcd + 1][cc]);
    o.z = f2bf(t_sh[tcd + 2][cc]); o.w = f2bf(t_sh[tcd + 3][cc]);
    *(ushort4*)&op[(size_t)rr * p.out_ld + r0 + tcd] = o;
  }
}

// ---------------- up GEMMs + fused silu*u epilogue; 64x128 tiles, 2-barrier loop ----------------
// blocks [0,512): shared  mt=bid>>4 (32), nt=bid&15 (16)
// blocks [512,512+4*QMAX): routed; mti=id>>2 from queue, ntile=id&3
__global__ __launch_bounds__(256) void k_up(
    const ushort* __restrict__ xb, const ushort* __restrict__ wguTs,
    const ushort* __restrict__ wguTr, const int* __restrict__ cnt,
    const int* __restrict__ ltok, const float* __restrict__ lw,
    const int* __restrict__ desc, const int* __restrict__ nmt,
    ushort* __restrict__ h_s, ushort* __restrict__ h_r)
{
  __shared__ ushort smem[(64 + 128) * 64];   // 24 KB: A 64x64 | B 128x64
  ushort* a_sh = smem;
  ushort* b_sh = smem + 64 * 64;
  ushort (*r_sh)[64] = (ushort(*)[64])smem;  // 8 KB epilogue alias
  const int tid = threadIdx.x, lane = tid & 63, wave = tid >> 6;
  const int wr = wave >> 1, wc = wave & 1;
  const int rb = lane & 15, rowoff = (lane >> 4) << 2;
  f32x4 acc[2][4] = {};
  const int bid = xcd_swz(blockIdx.x, (512 + 4 * QMAX) / 8);

  if (bid < 512) {
    const int mt = bid >> 4, nt = bid & 15;
    const ushort* Ab = xb + (size_t)mt * 64 * DHID;
    const ushort* Bb = wguTs + (size_t)nt * 128 * DHID;
    for (int k0 = 0; k0 < DHID; k0 += 64) {
      __syncthreads();
      stage64(Ab + k0, DHID, a_sh, tid);
      stage128(Bb + k0, DHID, b_sh, tid);
      __syncthreads();
      mfma_tile64(a_sh, b_sh, wr, wc, lane, acc);
    }
    __syncthreads();
#pragma unroll
    for (int m = 0; m < 2; m++)
#pragma unroll
      for (int p = 0; p < 2; p++) {
        f32x4 g = acc[m][2 * p], u = acc[m][2 * p + 1];
#pragma unroll
        for (int jj = 0; jj < 4; jj++) {
          float gv = g[jj];
          float hv = (gv / (1.f + __expf(-gv))) * u[jj];
          r_sh[wr * 32 + m * 16 + rowoff + jj][wc * 32 + p * 16 + rb] = f2bf(hv);
        }
      }
    __syncthreads();
    {
      const int row = tid >> 2, colE = (tid & 3) * 16;
      ushort* hp = &h_s[(size_t)(mt * 64 + row) * DHID + nt * 64 + colE];
      *(uint4*)hp = *(const uint4*)&r_sh[row][colE];
      *(uint4*)(hp + 8) = *(const uint4*)&r_sh[row][colE + 8];
    }
  } else {
    const int id = bid - 512;
    const int mti = id >> 2, ntile = id & 3;
    if (mti >= *nmt) return;
    const int d = desc[mti];
    const int e = d >> 16, s0 = d & 0xffff;
    const int c = cnt[e];
    int tok[2];
#pragma unroll
    for (int s = 0; s < 2; ++s) {
      int slot = s0 + s * 32 + (tid >> 3);
      if (slot >= c) slot = c - 1;
      tok[s] = ltok[e * CAP + slot];
    }
    const ushort* Bb = wguTr + ((size_t)e * 512 + ntile * 128) * DHID;
    for (int k0 = 0; k0 < DHID; k0 += 64) {
      __syncthreads();
      stage_gather64(xb, tok, k0, a_sh, tid);
      stage128(Bb + k0, DHID, b_sh, tid);
      __syncthreads();
      mfma_tile64(a_sh, b_sh, wr, wc, lane, acc);
    }
    __syncthreads();
#pragma unroll
    for (int m = 0; m < 2; m++)
#pragma unroll
      for (int jj = 0; jj < 4; jj++) {
        const int slot = s0 + wr * 32 + m * 16 + rowoff + jj;
        const float w = (slot < c) ? lw[e * CAP + slot] : 0.f;
#pragma unroll
        for (int p = 0; p < 2; p++) {
          float gv = acc[m][2 * p][jj];
          float hv = (gv / (1.f + __expf(-gv))) * acc[m][2 * p + 1][jj] * w;
          r_sh[wr * 32 + m * 16 + rowoff + jj][wc * 32 + p * 16 + rb] = f2bf(hv);
        }
      }
    __syncthreads();
    {
      const int row = tid >> 2, colE = (tid & 3) * 16;
      ushort* hp = &h_r[((size_t)e * CAP + s0 + row) * MR + ntile * 64 + colE];
      *(uint4*)hp = *(const uint4*)&r_sh[row][colE];
      *(uint4*)(hp + 8) = *(const uint4*)&r_sh[row][colE + 8];
    }
  }
}

// ---------------- down GEMMs (merged): 64x128 tiles, bf16 partials, no atomics ----------------
// blocks [0,256): shared  mt=bid>>3 (32), nt=bid&7 (8)
// blocks [256,256+8*QMAX): routed; mti=id>>3 from queue, nt=id&7
__global__ __launch_bounds__(256) void k_down(
    const ushort* __restrict__ h_s, const ushort* __restrict__ wdTs,
    const ushort* __restrict__ h_r, const ushort* __restrict__ wdTr,
    const int* __restrict__ desc, const int* __restrict__ nmt,
    ushort* __restrict__ ds, ushort* __restrict__ dr)
{
  __shared__ ushort smem[(64 + 128) * 64];   // 24 KB
  ushort* a_sh = smem;
  ushort* b_sh = smem + 64 * 64;
  ushort (*r_sh)[128] = (ushort(*)[128])smem;  // 16 KB epilogue alias
  const int tid = threadIdx.x, lane = tid & 63, wave = tid >> 6;
  const int wr = wave >> 1, wc = wave & 1;
  const int rb = lane & 15, rowoff = (lane >> 4) << 2;
  f32x4 acc[2][4] = {};
  const int bid = xcd_swz(blockIdx.x, (256 + 8 * QMAX) / 8);

  const ushort* Ab; const ushort* Bb;
  int K, rowbase, colbase; ushort* outp;
  if (bid < 256) {
    const int mt = bid >> 3, nt = bid & 7;
    Ab = h_s + (size_t)mt * 64 * DHID;
    Bb = wdTs + (size_t)nt * 128 * DHID;
    K = DHID; rowbase = mt * 64; colbase = nt * 128;
    outp = ds;
  } else {
    const int id = bid - 256;
    const int mti = id >> 3, nt = id & 7;
    if (mti >= *nmt) return;
    const int d = desc[mti];
    const int e = d >> 16, s0 = d & 0xffff;
    Ab = h_r + ((size_t)e * CAP + s0) * MR;
    Bb = wdTr + ((size_t)e * DHID + nt * 128) * MR;
    K = MR; rowbase = e * CAP + s0; colbase = nt * 128;
    outp = dr;
  }
  for (int k0 = 0; k0 < K; k0 += 64) {
    __syncthreads();
    stage64(Ab + k0, K, a_sh, tid);
    stage128(Bb + k0, K, b_sh, tid);
    __syncthreads();
    mfma_tile64(a_sh, b_sh, wr, wc, lane, acc);
  }
  __syncthreads();
#pragma unroll
  for (int m = 0; m < 2; m++)
#pragma unroll
    for (int n = 0; n < 4; n++) {
      f32x4 v = acc[m][n];
#pragma unroll
      for (int jj = 0; jj < 4; jj++)
        r_sh[wr * 32 + m * 16 + rowoff + jj][wc * 64 + n * 16 + rb] = f2bf(v[jj]);
    }
  __syncthreads();
  {
    const int row = tid >> 2, colE = (tid & 3) * 32;
    ushort* op = &outp[(size_t)(rowbase + row) * DHID + colbase + colE];
#pragma unroll
    for (int q = 0; q < 4; q++)
      *(uint4*)(op + q * 8) = *(const uint4*)&r_sh[row][colE + q * 8];
  }
}

// ---------------- combine: out[t] = ds[t] + dr[es1] + dr[es2]  (f32 out) ----------------
__global__ __launch_bounds__(256) void k_comb(
    const ushort* __restrict__ ds, const ushort* __restrict__ dr,
    const int* __restrict__ tslot, float* __restrict__ out)
{
  const int tid = threadIdx.x;
  const int t = blockIdx.x * 2 + (tid >> 7);
  const int d = (tid & 127) * 8;
  const int es1 = tslot[t * 2], es2 = tslot[t * 2 + 1];
  uint4 a = *(const uint4*)&ds[(size_t)t * DHID + d];
  float r[8];
  const ushort* ap = (const ushort*)&a;
#pragma unroll
  for (int k = 0; k < 8; ++k) r[k] = bf2f(ap[k]);
  if (es1 >= 0) {
    uint4 b = *(const uint4*)&dr[(size_t)es1 * DHID + d];
    const ushort* bp = (const ushort*)&b;
#pragma unroll
    for (int k = 0; k < 8; ++k) r[k] += bf2f(bp[k]);
  }
  if (es2 >= 0) {
    uint4 b = *(const uint4*)&dr[(size_t)es2 * DHID + d];
    const ushort* bp = (const ushort*)&b;
#pragma unroll
    for (int k = 0; k < 8; ++k) r[k] += bf2f(bp[k]);
  }
  float4* op = (float4*)&out[(size_t)t * DHID + d];
  op[0] = make_float4(r[0], r[1], r[2], r[3]);
  op[1] = make_float4(r[4], r[5], r[6], r[7]);
}

extern "C" void kernel_launch(void* const* d_in, const int* in_sizes, int n_in,
                              void* d_out, int out_size, void* d_ws, size_t ws_size,
                              hipStream_t stream) {
  const float* x    = (const float*)d_in[0];
  const float* rw   = (const float*)d_in[1];
  const float* wg_r = (const float*)d_in[2];
  const float* wu_r = (const float*)d_in[3];
  const float* wd_r = (const float*)d_in[4];
  const float* wg_s = (const float*)d_in[5];
  const float* wu_s = (const float*)d_in[6];
  const float* wd_s = (const float*)d_in[7];
  float* out = (float*)d_out;

  char* ws = (char*)d_ws;
  size_t off = 0;
  ushort* xb    = (ushort*)(ws + off); off += (size_t)T_TOK * DHID * 2;        // 4 MB
  ushort* wguTs = (ushort*)(ws + off); off += (size_t)2048 * DHID * 2;         // 4 MB  interleaved g/u rows
  ushort* wdTs  = (ushort*)(ws + off); off += (size_t)DHID * DHID * 2;         // 2 MB
  ushort* wguTr = (ushort*)(ws + off); off += (size_t)NEXP * 512 * DHID * 2;   // 16 MB interleaved per expert
  ushort* wdTr  = (ushort*)(ws + off); off += (size_t)NEXP * DHID * MR * 2;    // 8 MB
  ushort* h_s   = (ushort*)(ws + off); off += (size_t)T_TOK * DHID * 2;        // 4 MB
  ushort* h_r   = (ushort*)(ws + off); off += (size_t)NEXP * CAP * MR * 2;     // 4 MB
  ushort* ds    = (ushort*)(ws + off); off += (size_t)T_TOK * DHID * 2;        // 4 MB
  ushort* dr    = (ushort*)(ws + off); off += (size_t)NEXP * CAP * DHID * 2;   // 16 MB
  int*    cnt   = (int*)(ws + off);    off += 256;
  int*    ltok  = (int*)(ws + off);    off += (size_t)NEXP * CAP * 4;
  float*  lw    = (float*)(ws + off);  off += (size_t)NEXP * CAP * 4;
  int*    topi  = (int*)(ws + off);    off += (size_t)T_TOK * 4;
  float2* topw  = (float2*)(ws + off); off += (size_t)T_TOK * 8;
  int*    tslot = (int*)(ws + off);    off += (size_t)T_TOK * 2 * 4;
  int*    desc  = (int*)(ws + off);    off += (QMAX + 8) * 4;
  int*    nmt   = (int*)(ws + off);    off += 64;
  if (off > ws_size) return;

  k_prep<<<T_TOK / 16, 256, 0, stream>>>(x, rw, xb, topi, topw);
  k_build<<<NEXP, 256, 0, stream>>>(topi, topw, cnt, ltok, lw, tslot);
  k_queue<<<1, 64, 0, stream>>>(cnt, desc, nmt);

  TP p0 = {wg_r, wguTr,             DHID, MR,   DHID, 1, (long long)512 * DHID,  1024};
  TP p1 = {wu_r, wguTr + 16 * DHID, DHID, MR,   DHID, 1, (long long)512 * DHID,  2048};
  TP p2 = {wd_r, wdTr,              MR,   DHID, MR,   0, (long long)DHID * MR,   3072};
  TP p3 = {wg_s, wguTs,             DHID, MS,   DHID, 1, (long long)1024 * DHID, 3328};
  TP p4 = {wu_s, wguTs + 16 * DHID, DHID, MS,   DHID, 1, (long long)1024 * DHID, 3584};
  TP p5 = {wd_s, wdTs,              MS,   DHID, DHID, 0, (long long)MS,          3840};
  k_tpose<<<3840, 256, 0, stream>>>(p0, p1, p2, p3, p4, p5);

  k_up<<<512 + 4 * QMAX, 256, 0, stream>>>(xb, wguTs, wguTr, cnt, ltok, lw, desc, nmt, h_s, h_r);
  k_down<<<256 + 8 * QMAX, 256, 0, stream>>>(h_s, wdTs, h_r, wdTr, desc, nmt, ds, dr);
  k_comb<<<T_TOK / 2, 256, 0, stream>>>(ds, dr, tslot, out);
}